// Round 1
// baseline (129.884 us; speedup 1.0000x reference)
//
#include <hip/hip_runtime.h>
#include <math.h>

#define A_N 5
#define NC 20
#define FD 38
#define SD (FD*FD)        // 1444
#define BD 32
#define OD 50
#define SA (SD*A_N)       // 7220
#define IGN_T 0.6f
#define OBJ_S 5.0f

__device__ __forceinline__ float sigm(float x) { return 1.0f / (1.0f + expf(-x)); }

// ---------------- Kernel A: max IoU per (b,s,a) + n_pos flags ----------------
__global__ __launch_bounds__(256) void k_maxiou(
    const float* __restrict__ outputs, const float* __restrict__ targets,
    const float* __restrict__ anchors, float* __restrict__ miou,
    int* __restrict__ npos)
{
    __shared__ float g_tlx[OD], g_tly[OD], g_brx[OD], g_bry[OD], g_den[OD];
    __shared__ int s_cnt;
    const int b = blockIdx.y;
    const int tid = threadIdx.x;
    if (tid == 0) s_cnt = 0;
    __syncthreads();
    if (tid < OD) {
        const float* t = targets + (b * OD + tid) * 5;
        float tx = t[0], ty = t[1], tw = t[2], th = t[3], tc = t[4];
        if (tx + ty + tw + th + tc > 0.0f) {
            float gx = tx * FD, gy = ty * FD, gw = tw * FD, gh = th * FD;
            int k = atomicAdd(&s_cnt, 1);
            g_tlx[k] = gx - gw * 0.5f; g_tly[k] = gy - gh * 0.5f;
            g_brx[k] = gx + gw * 0.5f; g_bry[k] = gy + gh * 0.5f;
            g_den[k] = gw * gh + 1e-12f;   // area_b + eps
        }
    }
    __syncthreads();
    const int cnt = s_cnt;
    const int idx = blockIdx.x * 256 + tid;
    if (idx >= SA) return;
    const int a = idx / SD;
    const int s = idx - a * SD;
    const int i = s / FD, j = s - i * FD;

    const float* ob = outputs + ((size_t)b * (A_N * (5 + NC)) + a * (5 + NC)) * SD + s;
    float o0 = ob[0 * SD], o1 = ob[1 * SD], o2 = ob[2 * SD], o3 = ob[3 * SD];
    float aw = anchors[2 * a] * FD, ah = anchors[2 * a + 1] * FD;
    float px = sigm(o0) + (float)j;
    float py = sigm(o1) + (float)i;
    float pw = expf(o2) * aw;
    float ph = expf(o3) * ah;
    float ptlx = px - pw * 0.5f, ptly = py - ph * 0.5f;
    float pbrx = px + pw * 0.5f, pbry = py + ph * 0.5f;
    float areaA = pw * ph;

    float m = 0.0f;
    for (int o = 0; o < cnt; ++o) {
        float w = fmaxf(fminf(pbrx, g_brx[o]) - fmaxf(ptlx, g_tlx[o]), 0.0f);
        float h = fmaxf(fminf(pbry, g_bry[o]) - fmaxf(ptly, g_tly[o]), 0.0f);
        float inter = w * h;
        float iou = inter / (areaA + g_den[o] - inter);
        m = fmaxf(m, iou);
    }
    miou[((size_t)b * A_N + a) * SD + s] = m;
    if (m > IGN_T) atomicOr(&npos[b], 1);
}

// ---------------- Kernel B: responsible (cell,anchor) assignment -------------
// One thread per batch; ascending o => last-write-wins like numpy fancy assign.
__global__ __launch_bounds__(64) void k_assign(
    const float* __restrict__ targets, const float* __restrict__ anchors,
    int* __restrict__ resp)
{
    const int b = threadIdx.x;
    if (b >= BD) return;
    float aw[A_N], ah[A_N];
    for (int a = 0; a < A_N; ++a) { aw[a] = anchors[2*a] * FD; ah[a] = anchors[2*a+1] * FD; }
    for (int o = 0; o < OD; ++o) {
        const float* t = targets + (b * OD + o) * 5;
        float tx = t[0], ty = t[1], tw = t[2], th = t[3], tc = t[4];
        if (!(tx + ty + tw + th + tc > 0.0f)) continue;
        float gx = tx * FD, gy = ty * FD, gw = tw * FD, gh = th * FD;
        float gtlx = gx - gw * 0.5f, gtly = gy - gh * 0.5f;
        float gbrx = gx + gw * 0.5f, gbry = gy + gh * 0.5f;
        int cx = (int)floorf(gtlx);
        int cy = (int)floorf(gtly);
        int cell = cy * FD + cx;
        cell = min(max(cell, 0), SD - 1);
        int ci = cell / FD, cj = cell - ci * FD;
        float acx = (float)cj + 0.5f, acy = (float)ci + 0.5f;
        float areaB = gw * gh;
        float best = -1.0f; int bi = 0;
        for (int a = 0; a < A_N; ++a) {
            float w = fmaxf(fminf(acx + aw[a]*0.5f, gbrx) - fmaxf(acx - aw[a]*0.5f, gtlx), 0.0f);
            float h = fmaxf(fminf(acy + ah[a]*0.5f, gbry) - fmaxf(acy - ah[a]*0.5f, gtly), 0.0f);
            float inter = w * h;
            float iou = inter / (aw[a]*ah[a] + areaB - inter + 1e-12f);
            if (iou > best) { best = iou; bi = a; }
        }
        resp[((size_t)b * A_N + bi) * SD + cell] = o;
    }
}

// ---------------- Kernel C: loss ---------------------------------------------
__global__ __launch_bounds__(256) void k_loss(
    const float* __restrict__ outputs, const float* __restrict__ targets,
    const float* __restrict__ anchors, const float* __restrict__ miou,
    const int* __restrict__ npos, const int* __restrict__ resp,
    float* __restrict__ out)
{
    const int b = blockIdx.y;
    const int tid = threadIdx.x;
    const int idx = blockIdx.x * 256 + tid;
    float loss = 0.0f;
    if (idx < SA) {
        const int a = idx / SD;
        const int s = idx - a * SD;
        const int i = s / FD, j = s - i * FD;
        const size_t pos = ((size_t)b * A_N + a) * SD + s;
        const float* ob = outputs + ((size_t)b * (A_N * (5 + NC)) + a * (5 + NC)) * SD + s;
        float conf = sigm(ob[4 * SD]);
        float m = miou[pos];
        int ro = resp[pos];
        if (ro >= 0) {
            // iou loss at responsible position: mask = OBJ_SCALE, target = m
            float d = conf - m;
            loss += OBJ_S * OBJ_S * d * d;
            // box loss: pd = [sigm, sigm, exp, exp] (NO anchor scale on pd)
            const float* t = targets + (b * OD + ro) * 5;
            float gx = t[0] * FD, gy = t[1] * FD, gw = t[2] * FD, gh = t[3] * FD;
            int ct = (int)t[4];
            float aw = anchors[2 * a] * FD, ah = anchors[2 * a + 1] * FD;
            float dx = gx - ((float)j + 0.5f);
            float dy = gy - ((float)i + 0.5f);
            float dw = gw / aw;
            float dh = gh / ah;
            float e0 = sigm(ob[0]) - dx;
            float e1 = sigm(ob[SD]) - dy;
            float e2 = expf(ob[2 * SD]) - dw;
            float e3 = expf(ob[3 * SD]) - dh;
            loss += e0*e0 + e1*e1 + e2*e2 + e3*e3;
            // class loss: ce = -log_softmax(softmax(x))[ct]
            float x[NC];
            float xmax = -INFINITY;
            #pragma unroll
            for (int k = 0; k < NC; ++k) { x[k] = ob[(5 + k) * SD]; xmax = fmaxf(xmax, x[k]); }
            float esum = 0.0f;
            #pragma unroll
            for (int k = 0; k < NC; ++k) { x[k] = expf(x[k] - xmax); esum += x[k]; }
            float inv = 1.0f / esum;
            float pmax = 0.0f, pct = 0.0f;
            #pragma unroll
            for (int k = 0; k < NC; ++k) {
                float p = x[k] * inv; x[k] = p;
                pmax = fmaxf(pmax, p);
                pct = (k == ct) ? p : pct;
            }
            float e2s = 0.0f;
            #pragma unroll
            for (int k = 0; k < NC; ++k) e2s += expf(x[k] - pmax);
            loss += -(pct - (pmax + logf(e2s)));
        } else {
            bool ign = (npos[b] != 0) && (m >= IGN_T);
            if (!ign) loss += conf * conf;   // (conf*1 - 0)^2
        }
    }
    // block reduction: wave64 shuffle + LDS across 4 waves
    #pragma unroll
    for (int off = 32; off > 0; off >>= 1) loss += __shfl_down(loss, off);
    __shared__ float wsum[4];
    int lane = tid & 63, w = tid >> 6;
    if (lane == 0) wsum[w] = loss;
    __syncthreads();
    if (tid == 0) {
        float t = wsum[0] + wsum[1] + wsum[2] + wsum[3];
        atomicAdd(out, t * (1.0f / (float)BD));
    }
}

extern "C" void kernel_launch(void* const* d_in, const int* in_sizes, int n_in,
                              void* d_out, int out_size, void* d_ws, size_t ws_size,
                              hipStream_t stream) {
    (void)in_sizes; (void)n_in; (void)out_size; (void)ws_size;
    const float* outputs = (const float*)d_in[0];
    const float* targets = (const float*)d_in[1];
    const float* anchors = (const float*)d_in[2];
    float* out = (float*)d_out;

    const size_t n_pos_elems = (size_t)BD * A_N * SD;   // 231040
    float* miou = (float*)d_ws;
    int*   resp = (int*)((char*)d_ws + n_pos_elems * sizeof(float));
    int*   npos = (int*)((char*)d_ws + 2 * n_pos_elems * sizeof(float));

    hipMemsetAsync(out, 0, sizeof(float), stream);
    hipMemsetAsync(resp, 0xFF, n_pos_elems * sizeof(int), stream);  // -1
    hipMemsetAsync(npos, 0, BD * sizeof(int), stream);

    dim3 grid((SA + 255) / 256, BD);
    k_maxiou<<<grid, 256, 0, stream>>>(outputs, targets, anchors, miou, npos);
    k_assign<<<dim3(1), 64, 0, stream>>>(targets, anchors, resp);
    k_loss<<<grid, 256, 0, stream>>>(outputs, targets, anchors, miou, npos, resp, out);
}